// Round 3
// baseline (992.363 us; speedup 1.0000x reference)
//
#include <hip/hip_runtime.h>
#include <stdint.h>

#define NN 10000
#define NE 320000
#define DF 128
#define OD 128
#define NS 3

typedef __attribute__((ext_vector_type(8))) short bf16x8;
typedef __attribute__((ext_vector_type(16))) float f32x16;

static __device__ __forceinline__ uint32_t f2bf(float f) {
  uint32_t u = __float_as_uint(f);
  return (u + 0x7FFFu + ((u >> 16) & 1u)) >> 16;
}
static __device__ __forceinline__ float bflo(uint32_t u) { return __uint_as_float(u << 16); }
static __device__ __forceinline__ float bfhi(uint32_t u) { return __uint_as_float(u & 0xFFFF0000u); }

// truncation-pack relu (saves ~30% producer VALU vs RNE; err <= 2^-8 rel)
static __device__ __forceinline__ uint32_t relu2t(uint32_t a, uint32_t d) {
  float f0 = fmaxf(bflo(a) + bflo(d), 0.0f);
  float f1 = fmaxf(bfhi(a) + bfhi(d), 0.0f);
  return (__float_as_uint(f0) >> 16) | (__float_as_uint(f1) & 0xFFFF0000u);
}

static __device__ __forceinline__ int nbucket(int n) { return (n * 8) / NN; }  // 0..7

// ---------------------------------------------------------------------------
// Kernel 0: W2 -> W2T bf16, bmean = mean_s b2, and zero the sort control ints
// ---------------------------------------------------------------------------
__global__ __launch_bounds__(256) void prep_w2(
    const float* __restrict__ W2, const float* __restrict__ b2,
    unsigned short* __restrict__ w2t, float* __restrict__ bmean,
    int* __restrict__ ctrl)
{
  int tid = blockIdx.x * 256 + threadIdx.x;
  if (blockIdx.x == 0) ctrl[threadIdx.x] = 0;      // hist/cursor/starts/queues
  if (tid < NS * OD * OD) {
    int s = tid / (OD * OD);
    int r = tid % (OD * OD);
    int k = r / OD;
    int n = r % OD;
    w2t[(s * OD + n) * OD + k] = (unsigned short)f2bf(W2[tid]);
  }
  if (tid < OD) bmean[tid] = (b2[tid] + b2[OD + tid] + b2[2 * OD + tid]) * (1.0f / 3.0f);
}

// ---------------------------------------------------------------------------
// Sort kernels: counting sort of edges by 64 (srcRange, dstRange) buckets.
// ctrl layout (ints): [0:64) hist, [64:128) cursor, [128:193) bucketStart,
//                     [200:209) xcdStart, [212:220) xcdCur
// ---------------------------------------------------------------------------
__global__ __launch_bounds__(256) void edge_hist(
    const int* __restrict__ ei, int* __restrict__ ctrl)
{
  __shared__ int lh[64];
  int t = threadIdx.x;
  if (t < 64) lh[t] = 0;
  __syncthreads();
  int e = blockIdx.x * 256 + t;
  int k = nbucket(ei[e]) * 8 + nbucket(ei[NE + e]);
  atomicAdd(&lh[k], 1);
  __syncthreads();
  if (t < 64 && lh[t]) atomicAdd(&ctrl[t], lh[t]);
}

__global__ __launch_bounds__(64) void edge_scan(int* __restrict__ ctrl)
{
  if (threadIdx.x == 0) {
    int acc = 0;
    for (int i = 0; i < 64; i++) { ctrl[128 + i] = acc; acc += ctrl[i]; }
    ctrl[128 + 64] = acc;                       // == NE
    for (int x = 0; x < 8; x++) ctrl[200 + x] = ctrl[128 + 8 * x];
    ctrl[208] = NE;
  }
}

__global__ __launch_bounds__(256) void edge_scatter(
    const int* __restrict__ ei, int* __restrict__ ctrl, int* __restrict__ perm)
{
  int e = blockIdx.x * 256 + threadIdx.x;
  int k = nbucket(ei[e]) * 8 + nbucket(ei[NE + e]);
  int pos = ctrl[128 + k] + atomicAdd(&ctrl[64 + k], 1);
  perm[pos] = e;
}

// ---------------------------------------------------------------------------
// Kernel 1: per-node projections (layer-1 hoist), MFMA 32x32x16 bf16.
// ---------------------------------------------------------------------------
__global__ __launch_bounds__(256) void node_proj(
    const float* __restrict__ nf, const float* __restrict__ temporal,
    const float* __restrict__ W1, const float* __restrict__ b1,
    unsigned short* __restrict__ Qsrc, unsigned short* __restrict__ Qdst)
{
  __shared__ unsigned short Asm[8 * 64 * 8];
  __shared__ unsigned short Bsm[4 * 8 * 64 * 8];
  __shared__ float tsh[32];

  const int t = threadIdx.x;
  const int c = blockIdx.y;
  const int s = c >> 1, proj = c & 1;

  {
    int o = t & 127, qh = t >> 7;
    const float* wbase = W1 + (size_t)(s * 257 + proj * 128) * OD + o;
    int nt = o >> 5, lnlo = o & 31;
    #pragma unroll
    for (int r = 0; r < 8; r++) {
      int kh = qh * 8 + r;
      float v[8];
      #pragma unroll
      for (int j = 0; j < 8; j++) v[j] = wbase[(size_t)(kh * 8 + j) * OD];
      uint32_t pk[4];
      #pragma unroll
      for (int i = 0; i < 4; i++) pk[i] = f2bf(v[2 * i]) | (f2bf(v[2 * i + 1]) << 16);
      int q = kh >> 1, half = kh & 1;
      uint32_t* d = (uint32_t*)(Bsm + ((nt * 8 + q) * 64 + half * 32 + lnlo) * 8);
      d[0] = pk[0]; d[1] = pk[1]; d[2] = pk[2]; d[3] = pk[3];
    }
  }

  const int lane = t & 63, w = t >> 6;
  const int o = w * 32 + (lane & 31);
  const float w1gv = W1[(size_t)(s * 257 + 256) * OD + o];
  const float b1v = b1[s * OD + o];
  unsigned short* Qt = (proj == 0) ? Qsrc : Qdst;
  const int m = t >> 3, j16 = t & 7;

  for (int it = 0; it < 8; it++) {
    const int m0 = (blockIdx.x * 8 + it) * 32;
    if (m0 >= NN) break;

    if (t < 32) tsh[t] = (m0 + t < NN) ? temporal[m0 + t] : 0.0f;

    {
      int node = m0 + m;
      float v[16];
      if (node < NN) {
        const float4* p = (const float4*)(nf + (size_t)node * DF + j16 * 16);
        #pragma unroll
        for (int i = 0; i < 4; i++) {
          float4 x = p[i];
          v[4 * i] = x.x; v[4 * i + 1] = x.y; v[4 * i + 2] = x.z; v[4 * i + 3] = x.w;
        }
      } else {
        #pragma unroll
        for (int i = 0; i < 16; i++) v[i] = 0.0f;
      }
      uint32_t pk[8];
      #pragma unroll
      for (int i = 0; i < 8; i++) pk[i] = f2bf(v[2 * i]) | (f2bf(v[2 * i + 1]) << 16);
      uint32_t* d0 = (uint32_t*)(Asm + (j16 * 64 + (m ^ j16)) * 8);
      uint32_t* d1 = (uint32_t*)(Asm + (j16 * 64 + ((32 + m) ^ j16)) * 8);
      d0[0] = pk[0]; d0[1] = pk[1]; d0[2] = pk[2]; d0[3] = pk[3];
      d1[0] = pk[4]; d1[1] = pk[5]; d1[2] = pk[6]; d1[3] = pk[7];
    }
    __syncthreads();

    f32x16 C;
    #pragma unroll
    for (int i = 0; i < 16; i++) C[i] = 0.0f;
    #pragma unroll
    for (int q = 0; q < 8; q++) {
      bf16x8 a = *(const bf16x8*)(Asm + (q * 64 + (lane ^ q)) * 8);
      bf16x8 b = *(const bf16x8*)(Bsm + ((w * 8 + q) * 64 + lane) * 8);
      C = __builtin_amdgcn_mfma_f32_32x32x16_bf16(a, b, C, 0, 0, 0);
    }

    #pragma unroll
    for (int r = 0; r < 16; r++) {
      int row = (r & 3) + 8 * (r >> 2) + 4 * (lane >> 5);
      int node = m0 + row;
      if (node < NN) {
        float val = C[r];
        if (proj == 0) val += b1v + tsh[row] * w1gv;
        else           val -= tsh[row] * w1gv;
        Qt[(size_t)node * (NS * OD) + s * OD + o] = (unsigned short)f2bf(val);
      }
    }
    __syncthreads();
  }
}

// ---------------------------------------------------------------------------
// Kernel 2: edge kernel over SORTED edges with per-XCD work queues.
// Block reads its physical XCC_ID, pulls 128-edge chunks from its own XCD's
// bucket-sorted range (working set ~2 MB -> L2-resident), steals when empty.
// ---------------------------------------------------------------------------
__global__ __launch_bounds__(256) void edge_mlp(
    const unsigned short* __restrict__ Qsrc, const unsigned short* __restrict__ Qdst,
    const unsigned short* __restrict__ W2T, const float* __restrict__ bmean,
    const int* __restrict__ ei, const int* __restrict__ perm,
    const int* __restrict__ xcdStart, int* __restrict__ xcdCur,
    float* __restrict__ out)
{
  __shared__ unsigned short hsm[NS * 8 * 64 * 8];   // 24 KB, swizzled frag layout
  __shared__ int psm[128];                           // perm values for 4 subtiles
  __shared__ int chunkShared;

  const int t = threadIdx.x;
  const int lane = t & 63, w = t >> 6;
  const int nlo = lane & 31, khi = lane >> 5;

  bf16x8 bfrag[NS][8];
  {
    int n = w * 32 + nlo;
    #pragma unroll
    for (int s = 0; s < NS; s++) {
      const unsigned short* base = W2T + ((s * OD + n) * OD + khi * 8);
      #pragma unroll
      for (int q = 0; q < 8; q++)
        bfrag[s][q] = *(const bf16x8*)(base + q * 16);
    }
  }
  const float bmv = bmean[w * 32 + nlo];

  const int m = t >> 3, j16 = t & 7;   // producer mapping: 8 lanes/edge

  int myx;
  asm volatile("s_getreg_b32 %0, hwreg(HW_REG_XCC_ID)" : "=s"(myx));
  myx &= 7;

  for (int qi = 0; qi < 8; qi++) {
    const int q = (myx + qi) & 7;
    const int S = xcdStart[q], E = xcdStart[q + 1];
    const int tiles = (E - S + 127) >> 7;

    while (true) {
      if (t == 0) chunkShared = atomicAdd(&xcdCur[q], 1);
      __syncthreads();
      const int c128 = chunkShared;
      __syncthreads();
      if (c128 >= tiles) break;
      const int base = S + (c128 << 7);

      // gather indices for the 4 subtiles; stash perm values in LDS
      int sn[4], dn[4];
      #pragma unroll
      for (int tt = 0; tt < 4; tt++) {
        int p = base + tt * 32 + m;
        if (p >= E) p = E - 1;
        int e = perm[p];
        sn[tt] = ei[e];
        dn[tt] = ei[NE + e];
        if (j16 == 0) psm[tt * 32 + m] = e;
      }

      uint4 G[12], G2[12];
      {
        const unsigned short* ps = Qsrc + (size_t)sn[0] * (NS * OD) + j16 * 16;
        const unsigned short* pd = Qdst + (size_t)dn[0] * (NS * OD) + j16 * 16;
        #pragma unroll
        for (int s = 0; s < NS; s++) {
          G[4 * s + 0] = *(const uint4*)(ps + s * OD);
          G[4 * s + 1] = *(const uint4*)(ps + s * OD + 8);
          G[4 * s + 2] = *(const uint4*)(pd + s * OD);
          G[4 * s + 3] = *(const uint4*)(pd + s * OD + 8);
        }
      }

      #pragma unroll
      for (int tt = 0; tt < 4; tt++) {
        // ---- producer: h = relu(src + dst) -> LDS (swizzled frag layout) ----
        #pragma unroll
        for (int s = 0; s < NS; s++) {
          uint4 a0 = G[4 * s + 0], a1 = G[4 * s + 1];
          uint4 d0 = G[4 * s + 2], d1 = G[4 * s + 3];
          uint4 w0, w1;
          w0.x = relu2t(a0.x, d0.x); w0.y = relu2t(a0.y, d0.y);
          w0.z = relu2t(a0.z, d0.z); w0.w = relu2t(a0.w, d0.w);
          w1.x = relu2t(a1.x, d1.x); w1.y = relu2t(a1.y, d1.y);
          w1.z = relu2t(a1.z, d1.z); w1.w = relu2t(a1.w, d1.w);
          *(uint4*)(hsm + ((s * 8 + j16) * 64 + (m ^ j16)) * 8) = w0;
          *(uint4*)(hsm + ((s * 8 + j16) * 64 + ((32 + m) ^ j16)) * 8) = w1;
        }

        if (tt < 3) {
          const unsigned short* ps = Qsrc + (size_t)sn[tt + 1] * (NS * OD) + j16 * 16;
          const unsigned short* pd = Qdst + (size_t)dn[tt + 1] * (NS * OD) + j16 * 16;
          #pragma unroll
          for (int s = 0; s < NS; s++) {
            G2[4 * s + 0] = *(const uint4*)(ps + s * OD);
            G2[4 * s + 1] = *(const uint4*)(ps + s * OD + 8);
            G2[4 * s + 2] = *(const uint4*)(pd + s * OD);
            G2[4 * s + 3] = *(const uint4*)(pd + s * OD + 8);
          }
        }
        __syncthreads();

        // ---- consumer: C = sum_s h_s @ W2_s ----
        f32x16 C;
        #pragma unroll
        for (int i = 0; i < 16; i++) C[i] = 0.0f;
        #pragma unroll
        for (int s = 0; s < NS; s++) {
          #pragma unroll
          for (int qq = 0; qq < 8; qq++) {
            bf16x8 a = *(const bf16x8*)(hsm + ((s * 8 + qq) * 64 + (lane ^ qq)) * 8);
            C = __builtin_amdgcn_mfma_f32_32x32x16_bf16(a, bfrag[s][qq], C, 0, 0, 0);
          }
        }

        // ---- epilogue: out[perm] = C/3 + bmean (predicated on real edges) ----
        #pragma unroll
        for (int r = 0; r < 16; r++) {
          int row = (r & 3) + 8 * (r >> 2) + 4 * khi;
          int pos = base + tt * 32 + row;
          if (pos < E) {
            int oe = psm[tt * 32 + row];
            out[(size_t)oe * OD + w * 32 + nlo] = C[r] * (1.0f / 3.0f) + bmv;
          }
        }
        __syncthreads();

        #pragma unroll
        for (int i = 0; i < 12; i++) G[i] = G2[i];
      }
    }
  }
}

extern "C" void kernel_launch(void* const* d_in, const int* in_sizes, int n_in,
                              void* d_out, int out_size, void* d_ws, size_t ws_size,
                              hipStream_t stream) {
  const float* nf       = (const float*)d_in[0];
  const float* temporal = (const float*)d_in[1];
  const float* W1       = (const float*)d_in[2];
  const float* b1       = (const float*)d_in[3];
  const float* W2       = (const float*)d_in[4];
  const float* b2       = (const float*)d_in[5];
  const int*   ei       = (const int*)d_in[6];
  float* out = (float*)d_out;

  char* ws = (char*)d_ws;
  unsigned short* Qsrc = (unsigned short*)ws;                       // 7,680,000 B
  unsigned short* Qdst = (unsigned short*)(ws + 7680000);           // 7,680,000 B
  unsigned short* W2T  = (unsigned short*)(ws + 15360000);          // 98,304 B
  float*          bmv  = (float*)(ws + 15360000 + 98304);           // 512 B
  int*            ctrl = (int*)(ws + 15360000 + 98304 + 512);       // 256 ints
  int*            perm = (int*)(ws + 15360000 + 98304 + 512 + 1024);// 1,280,000 B

  prep_w2     <<<dim3(192),    dim3(256), 0, stream>>>(W2, b2, W2T, bmv, ctrl);
  edge_hist   <<<dim3(1250),   dim3(256), 0, stream>>>(ei, ctrl);
  edge_scan   <<<dim3(1),      dim3(64),  0, stream>>>(ctrl);
  edge_scatter<<<dim3(1250),   dim3(256), 0, stream>>>(ei, ctrl, perm);
  node_proj   <<<dim3(40, 6),  dim3(256), 0, stream>>>(nf, temporal, W1, b1, Qsrc, Qdst);
  edge_mlp    <<<dim3(2500),   dim3(256), 0, stream>>>(Qsrc, Qdst, W2T, bmv, ei, perm,
                                                       ctrl + 200, ctrl + 212, out);
}